// Round 1
// baseline (838.018 us; speedup 1.0000x reference)
//
#include <hip/hip_runtime.h>

// SNN layer: i[t,b,o] = sum_i x[b,i,t] * w[i,o]; then per-(b,o) sequential
// leaky-integrate-fire scan over t. Output spikes (0/1) as fp32, [B, O, T].
//
// Numerics: spike decisions (v >= 1.0) are razor-thin relative to fp32
// rounding of i (~1.8e5 magnitude). All accumulation + scan in fp64 to match
// the float64 numpy reference with ~zero flip probability.

#define NB 64
#define NI 512
#define NO 512
#define NT 500
#define OT 64     // outputs per block
#define KC 64     // K-chunk staged in LDS
#define TT 32     // t-chunk per scan round

__global__ __launch_bounds__(256, 2)
void snn_fused(const float* __restrict__ xg, const float* __restrict__ wg,
               float* __restrict__ yg) {
    __shared__ double xs[KC][TT];   // 16 KB
    __shared__ double wsh[KC][OT];  // 32 KB
    __shared__ double ib[TT][OT];   // 16 KB  -> 64 KB total, 2 blocks/CU

    const int tid = threadIdx.x;
    const int b   = blockIdx.y;
    const int o0  = blockIdx.x * OT;
    const int o   = tid & 63;
    const int tg  = tid >> 6;       // 0..3 (wave index; uniform per wave)

    const double alpha = 0.001 / 50.0;   // MS / TAU in double
    double v = 0.0;                      // persistent membrane (threads tid<64)

    for (int tc = 0; tc < NT; tc += TT) {
        const int tlim = (NT - tc < TT) ? (NT - tc) : TT;

        double acc[8];
        #pragma unroll
        for (int j = 0; j < 8; ++j) acc[j] = 0.0;

        for (int kc = 0; kc < NI; kc += KC) {
            __syncthreads();   // previous chunk's LDS reads complete

            // --- stage x tile: KC x TT = 2048 floats, 8 per thread ---
            {
                const int k   = tid >> 2;        // 0..63
                const int tt0 = (tid & 3) * 8;   // 0,8,16,24
                const float* px = xg + ((size_t)(b * NI + kc + k)) * NT + tc + tt0;
                if (tlim == TT) {
                    float4 f0 = *(const float4*)(px);
                    float4 f1 = *(const float4*)(px + 4);
                    xs[k][tt0+0]=f0.x; xs[k][tt0+1]=f0.y; xs[k][tt0+2]=f0.z; xs[k][tt0+3]=f0.w;
                    xs[k][tt0+4]=f1.x; xs[k][tt0+5]=f1.y; xs[k][tt0+6]=f1.z; xs[k][tt0+7]=f1.w;
                } else {
                    #pragma unroll
                    for (int e = 0; e < 8; ++e) {
                        const int t_ = tc + tt0 + e;
                        xs[k][tt0+e] = (t_ < NT) ? (double)px[e] : 0.0;
                    }
                }
            }
            // --- stage w tile: KC x OT = 4096 floats, 16 per thread ---
            {
                const int oo = (tid & 15) * 4;   // 0..60
                const int kb = tid >> 4;         // 0..15
                #pragma unroll
                for (int r = 0; r < 4; ++r) {
                    const int k = kb + r * 16;
                    float4 f = *(const float4*)(wg + (size_t)(kc + k) * NO + o0 + oo);
                    wsh[k][oo+0]=f.x; wsh[k][oo+1]=f.y; wsh[k][oo+2]=f.z; wsh[k][oo+3]=f.w;
                }
            }
            __syncthreads();

            // --- fp64 inner product: 8 t's per thread, 1 o ---
            #pragma unroll 4
            for (int k = 0; k < KC; ++k) {
                const double wv = wsh[k][o];
                const double* xr = &xs[k][tg * 8];
                #pragma unroll
                for (int j = 0; j < 8; ++j) acc[j] += xr[j] * wv;
            }
        }

        __syncthreads();
        #pragma unroll
        for (int j = 0; j < 8; ++j) ib[tg * 8 + j][o] = acc[j];
        __syncthreads();

        // --- sequential LIF scan on wave 0; v persists in registers ---
        if (tid < 64) {
            float sp[TT];
            for (int t = 0; t < tlim; ++t) {
                const double it = ib[t][o];
                v += (it - v) * alpha;
                const bool s = (v >= 1.0);
                sp[t] = s ? 1.0f : 0.0f;
                if (s) v = 0.0;
            }
            float* py = yg + ((size_t)(b * NO + o0 + o)) * NT + tc;
            for (int q = 0; q < tlim / 4; ++q) {
                *(float4*)(py + q * 4) =
                    make_float4(sp[q*4], sp[q*4+1], sp[q*4+2], sp[q*4+3]);
            }
        }
    }
}

extern "C" void kernel_launch(void* const* d_in, const int* in_sizes, int n_in,
                              void* d_out, int out_size, void* d_ws, size_t ws_size,
                              hipStream_t stream) {
    const float* x = (const float*)d_in[0];   // [64, 512, 500]
    const float* w = (const float*)d_in[1];   // [512, 512]
    float* y = (float*)d_out;                 // [64, 512, 500]
    (void)in_sizes; (void)n_in; (void)out_size; (void)d_ws; (void)ws_size;

    dim3 grid(NO / OT, NB);   // (8, 64) = 512 blocks
    snn_fused<<<grid, 256, 0, stream>>>(x, w, y);
}

// Round 4
// 523.932 us; speedup vs baseline: 1.5995x; 1.5995x over previous
//
#include <hip/hip_runtime.h>

// SNN layer on MI355X: i[t,b,o] = sum_k x[b,k,t] * w[k,o], then per-(b,o)
// sequential leaky-integrate-fire scan over t. Spikes (0/1) as fp32 [B,O,T].
//
// Numerics: spike decision v>=1.0 is razor-thin vs fp32 rounding of i
// (|i|~1.8e5) -> everything fp64 (round-1 scalar fp64 passed, absmax 0.0).
//
// Round 2/3 post-mortem: f64 MFMA path failed twice with verified-correct
// fragment layouts -> v_mfma_f64_16x16x4_f64 likely absent/inert on gfx950
// (MI355X spec: f64 matrix == f64 vector == 78.6 TF, the "no such MFMA"
// signature). Same ceiling either way -> optimized f64 VECTOR GEMM:
// 16 fp64 accs/thread (8t x 2o), b128 LDS reads, batched scan loads.

#define NB 64
#define NI 512
#define NO 512
#define NT 500
#define OT 64          // o per block
#define TT 64          // t per chunk (scan granularity)
#define KC 32          // k staged per LDS window
#define TP (TT + 2)
#define OP (OT + 2)

typedef double d2 __attribute__((ext_vector_type(2)));

__global__ __launch_bounds__(256, 2)
void snn_v2(const float* __restrict__ xg, const float* __restrict__ wg,
            float* __restrict__ yg) {
    // xs+wsh for GEMM; ib (scan input) aliases the same 4224 doubles exactly.
    __shared__ double smem[KC * TP + KC * OP];            // 33,792 B
    double (*xs)[TP]  = (double(*)[TP])smem;              // [KC][TP]
    double (*wsh)[OP] = (double(*)[OP])(smem + KC * TP);  // [KC][OP]
    double (*ib)[OP]  = (double(*)[OP])smem;              // [TT][OP]

    const int tid = threadIdx.x;
    const int p2  = (tid & 31) * 2;   // thread's o-pair base (0..62)
    const int t0  = (tid >> 5) * 8;   // thread's 8-t group base (0..56)

    // XCD swizzle: 8 o-tile blocks of one batch b -> same XCD -> x[b] L2-hot.
    const int L  = blockIdx.x;               // 0..511
    const int b  = (L & 7) + ((L >> 6) << 3);
    const int o0 = ((L >> 3) & 7) * OT;

    const int sk = tid >> 3;          // staging row 0..31
    const int se = (tid & 7) * 8;     // staging col 0..56

    const double alpha = 0.001 / 50.0;
    double v = 0.0;                   // persistent membrane (threads 0..63)

    for (int tc = 0; tc < NT; tc += TT) {
        const int tlim = (NT - tc < TT) ? (NT - tc) : TT;

        double a0[8], a1[8];
        #pragma unroll
        for (int j = 0; j < 8; ++j) { a0[j] = 0.0; a1[j] = 0.0; }

        for (int kc = 0; kc < NI; kc += KC) {
            __syncthreads();   // prior window's reads / prior scan complete

            // ---- stage x tile [KC][TT] f32->f64, 8 elems/thread ----
            {
                const float* px = xg + ((size_t)(b * NI + kc + sk)) * NT + tc + se;
                double* dx = &xs[sk][se];
                if (tlim == TT) {
                    #pragma unroll
                    for (int e = 0; e < 2; ++e) {
                        float4 f = ((const float4*)px)[e];
                        d2 lo = {(double)f.x, (double)f.y};
                        d2 hi = {(double)f.z, (double)f.w};
                        *(d2*)(dx + e * 4)     = lo;
                        *(d2*)(dx + e * 4 + 2) = hi;
                    }
                } else {
                    #pragma unroll
                    for (int e = 0; e < 8; ++e) {
                        double val = 0.0;                  // zero-pad t >= tlim
                        if (se + e < tlim) val = (double)px[e];
                        dx[e] = val;
                    }
                }
            }
            // ---- stage w tile [KC][OT] f32->f64, 8 elems/thread ----
            {
                const float* pw = wg + (size_t)(kc + sk) * NO + o0 + se;
                double* dw = &wsh[sk][se];
                #pragma unroll
                for (int e = 0; e < 2; ++e) {
                    float4 f = ((const float4*)pw)[e];
                    d2 lo = {(double)f.x, (double)f.y};
                    d2 hi = {(double)f.z, (double)f.w};
                    *(d2*)(dw + e * 4)     = lo;
                    *(d2*)(dw + e * 4 + 2) = hi;
                }
            }
            __syncthreads();

            // ---- fp64 inner product: 16 accs (8t x 2o) per thread ----
            // per k: 1 b128 (w-pair, coalesced) + 4 b128 (x, wave-uniform
            // broadcast) feeding 16 v_fma_f64 (64 cy) -> compute-bound.
            #pragma unroll 4
            for (int k = 0; k < KC; ++k) {
                const d2 w2 = *(const d2*)&wsh[k][p2];
                double x8[8];
                #pragma unroll
                for (int e = 0; e < 4; ++e)
                    *(d2*)&x8[e * 2] = *(const d2*)&xs[k][t0 + e * 2];
                #pragma unroll
                for (int j = 0; j < 8; ++j) {
                    a0[j] += x8[j] * w2[0];
                    a1[j] += x8[j] * w2[1];
                }
            }
        }

        __syncthreads();   // all fragment reads done; smem becomes ib
        #pragma unroll
        for (int j = 0; j < 8; ++j) {
            d2 c = {a0[j], a1[j]};
            *(d2*)&ib[t0 + j][p2] = c;
        }
        __syncthreads();

        // ---- sequential LIF scan, wave 0, batched loads ----
        // Tail rows (t >= tlim) are EXACT zeros (x zero-padded), and this
        // only happens in the final chunk, so running them is harmless;
        // stores are bounded by tlim.
        if (tid < 64) {
            float* py = yg + ((size_t)(b * NO + o0 + tid)) * NT + tc;
            for (int tb = 0; tb < TT; tb += 16) {
                double iv[16];
                #pragma unroll
                for (int u = 0; u < 16; ++u) iv[u] = ib[tb + u][tid];
                float fv[16];
                #pragma unroll
                for (int u = 0; u < 16; ++u) {
                    v += (iv[u] - v) * alpha;
                    const bool s = (v >= 1.0);
                    fv[u] = s ? 1.0f : 0.0f;
                    if (s) v = 0.0;
                }
                #pragma unroll
                for (int q = 0; q < 4; ++q) {
                    if (tb + q * 4 < tlim)
                        *(float4*)(py + tb + q * 4) =
                            make_float4(fv[q*4], fv[q*4+1], fv[q*4+2], fv[q*4+3]);
                }
            }
        }
    }
}

extern "C" void kernel_launch(void* const* d_in, const int* in_sizes, int n_in,
                              void* d_out, int out_size, void* d_ws, size_t ws_size,
                              hipStream_t stream) {
    const float* x = (const float*)d_in[0];   // [64, 512, 500]
    const float* w = (const float*)d_in[1];   // [512, 512]
    float* y = (float*)d_out;                 // [64, 512, 500]
    (void)in_sizes; (void)n_in; (void)out_size; (void)d_ws; (void)ws_size;

    snn_v2<<<512, 256, 0, stream>>>(x, w, y);
}

// Round 5
// 480.041 us; speedup vs baseline: 1.7457x; 1.0914x over previous
//
#include <hip/hip_runtime.h>

// SNN layer on MI355X, two-kernel design.
//   K1 (snn_gemm): i[t, b*512+o] = sum_k x[b,k,t] * w[k,o]  (fp64, to d_ws)
//   K2 (snn_scan): per-channel sequential LIF over t, spikes fp32 -> d_out
//
// Numerics: spike decision v>=1.0 is razor-thin vs fp32 rounding of i
// (|i|~1.8e5) -> all accumulation + scan in fp64 (rounds 1/4 passed, absmax 0).
//
// Round-4 post-mortem: fused kernel was structure-bound, not FMA-bound:
// VALUBusy 42% == pure-fp64-FMA fraction (214us floor / 524us); rest was LDS
// oversubscription (5 B/FMA-lane vs 2 sustainable) + 2 blocks/CU occupancy +
// scan/barrier serialization. K1 fixes intensity (broadcast x-frags,
// conflict-free strided w-frags, 4t x 8o per thread) and occupancy (2048
// blocks, 4/CU). K2 is a tiny BW-bound streamer (~197 MB).
//
// f64 MFMA is avoided: two clean attempts faulted (likely absent on gfx950);
// its ceiling equals the vector rate anyway.
//
// Fallback: if ws_size < 131 MB, run the proven round-4 fused kernel.

#define NB 64
#define NI 512
#define NO 512
#define NT 500
#define BO (NB * NO)          // 32768 channels

typedef double d2 __attribute__((ext_vector_type(2)));

// ===================== K1: fp64 GEMM to workspace =====================
#define K1_TT 64              // t-tile
#define K1_OT 128             // o-tile
#define K1_KC 16              // k per LDS window
#define XP (K1_TT + 2)
#define WP (K1_OT + 2)

__global__ __launch_bounds__(256, 4)
void snn_gemm(const float* __restrict__ xg, const float* __restrict__ wg,
              double* __restrict__ iw) {
    __shared__ double xs[K1_KC][XP];    //  8.4 KB
    __shared__ double wsh[K1_KC][WP];   // 16.6 KB -> 25 KB total, 4 blocks/CU

    const int tid = threadIdx.x;
    const int g   = tid & 15;     // o-group: owns o = o0 + g + 16q, q=0..7
    const int tt  = tid >> 4;     // t-subrow: owns t = t0 + tt + 16j, j=0..3

    // bijective XCD swizzle (nwg=2048, %8==0): all tiles of 8 consecutive
    // batches land on one XCD -> x[b] and w stay L2-resident.
    const int L     = blockIdx.x;
    const int wgid  = (L & 7) * 256 + (L >> 3);
    const int b     = wgid >> 5;          // 32 tiles per batch
    const int o0    = ((wgid >> 3) & 3) * K1_OT;
    const int t0    = (wgid & 7) * K1_TT;

    // staging map: row sk for both tiles
    const int sk = tid >> 4;          // 0..15
    const int xe = (tid & 15) * 4;    // x col (floats), 0..60
    const int we = (tid & 15) * 8;    // w col (floats), 0..120

    double acc[4][8];
    #pragma unroll
    for (int j = 0; j < 4; ++j)
        #pragma unroll
        for (int q = 0; q < 8; ++q) acc[j][q] = 0.0;

    const bool full = (t0 + K1_TT <= NT);   // only last t-tile is partial

    for (int kc = 0; kc < NI; kc += K1_KC) {
        __syncthreads();
        // ---- stage x [KC][64] f32->f64 (4 floats/thread) ----
        {
            const float* px = xg + ((size_t)(b * NI + kc + sk)) * NT + t0 + xe;
            if (full) {
                float4 f = *(const float4*)px;
                xs[sk][xe+0] = f.x; xs[sk][xe+1] = f.y;
                xs[sk][xe+2] = f.z; xs[sk][xe+3] = f.w;
            } else {
                #pragma unroll
                for (int e = 0; e < 4; ++e) {
                    double val = 0.0;
                    if (t0 + xe + e < NT) val = (double)px[e];
                    xs[sk][xe+e] = val;
                }
            }
        }
        // ---- stage w [KC][128] f32->f64 (8 floats/thread) ----
        {
            const float* pw = wg + (size_t)(kc + sk) * NO + o0 + we;
            float4 f0 = ((const float4*)pw)[0];
            float4 f1 = ((const float4*)pw)[1];
            wsh[sk][we+0] = f0.x; wsh[sk][we+1] = f0.y;
            wsh[sk][we+2] = f0.z; wsh[sk][we+3] = f0.w;
            wsh[sk][we+4] = f1.x; wsh[sk][we+5] = f1.y;
            wsh[sk][we+6] = f1.z; wsh[sk][we+7] = f1.w;
        }
        __syncthreads();

        // ---- fp64 inner: 32 FMA per thread per k ----
        // x-frag: 4 addrs/wave, 16-way broadcast (free).
        // w-frag: per q, 16 lanes read contiguous 128 B (conflict-free).
        #pragma unroll 4
        for (int k = 0; k < K1_KC; ++k) {
            double xf[4], wf[8];
            #pragma unroll
            for (int j = 0; j < 4; ++j) xf[j] = xs[k][tt + 16 * j];
            #pragma unroll
            for (int q = 0; q < 8; ++q) wf[q] = wsh[k][g + 16 * q];
            #pragma unroll
            for (int j = 0; j < 4; ++j)
                #pragma unroll
                for (int q = 0; q < 8; ++q) acc[j][q] += xf[j] * wf[q];
        }
    }

    // ---- store: iw[t][b*NO + o], 16-lane-contiguous segments ----
    double* pb = iw + (size_t)b * NO + o0 + g;
    #pragma unroll
    for (int j = 0; j < 4; ++j) {
        const int t = t0 + tt + 16 * j;
        if (t < NT) {
            double* pr = pb + (size_t)t * BO;
            #pragma unroll
            for (int q = 0; q < 8; ++q) pr[16 * q] = acc[j][q];
        }
    }
}

// ===================== K2: sequential LIF scan =====================
#define SB 20                 // t-batch (500 = 25*20)

__global__ __launch_bounds__(64)
void snn_scan(const double* __restrict__ iw, float* __restrict__ yg) {
    const int ch = blockIdx.x * 64 + threadIdx.x;   // b*512+o
    const double alpha = 0.001 / 50.0;
    double v = 0.0;
    float* py = yg + (size_t)ch * NT;

    for (int tb = 0; tb < NT; tb += SB) {
        double iv[SB];
        #pragma unroll
        for (int u = 0; u < SB; ++u) iv[u] = iw[(size_t)(tb + u) * BO + ch];
        float fv[SB];
        #pragma unroll
        for (int u = 0; u < SB; ++u) {
            v += (iv[u] - v) * alpha;
            const bool s = (v >= 1.0);
            fv[u] = s ? 1.0f : 0.0f;
            if (s) v = 0.0;
        }
        #pragma unroll
        for (int q = 0; q < SB / 4; ++q)
            *(float4*)(py + tb + 4 * q) =
                make_float4(fv[4*q], fv[4*q+1], fv[4*q+2], fv[4*q+3]);
    }
}

// ===================== fallback: round-4 fused kernel (proven) =====================
#define OT 64
#define TT 64
#define KC 32
#define TP (TT + 2)
#define OP (OT + 2)

__global__ __launch_bounds__(256, 2)
void snn_v2(const float* __restrict__ xg, const float* __restrict__ wg,
            float* __restrict__ yg) {
    __shared__ double smem[KC * TP + KC * OP];
    double (*xs)[TP]  = (double(*)[TP])smem;
    double (*wsh)[OP] = (double(*)[OP])(smem + KC * TP);
    double (*ib)[OP]  = (double(*)[OP])smem;

    const int tid = threadIdx.x;
    const int p2  = (tid & 31) * 2;
    const int t0  = (tid >> 5) * 8;

    const int L  = blockIdx.x;
    const int b  = (L & 7) + ((L >> 6) << 3);
    const int o0 = ((L >> 3) & 7) * OT;

    const int sk = tid >> 3;
    const int se = (tid & 7) * 8;

    const double alpha = 0.001 / 50.0;
    double v = 0.0;

    for (int tc = 0; tc < NT; tc += TT) {
        const int tlim = (NT - tc < TT) ? (NT - tc) : TT;

        double a0[8], a1[8];
        #pragma unroll
        for (int j = 0; j < 8; ++j) { a0[j] = 0.0; a1[j] = 0.0; }

        for (int kc = 0; kc < NI; kc += KC) {
            __syncthreads();
            {
                const float* px = xg + ((size_t)(b * NI + kc + sk)) * NT + tc + se;
                double* dx = &xs[sk][se];
                if (tlim == TT) {
                    #pragma unroll
                    for (int e = 0; e < 2; ++e) {
                        float4 f = ((const float4*)px)[e];
                        d2 lo = {(double)f.x, (double)f.y};
                        d2 hi = {(double)f.z, (double)f.w};
                        *(d2*)(dx + e * 4)     = lo;
                        *(d2*)(dx + e * 4 + 2) = hi;
                    }
                } else {
                    #pragma unroll
                    for (int e = 0; e < 8; ++e) {
                        double val = 0.0;
                        if (se + e < tlim) val = (double)px[e];
                        dx[e] = val;
                    }
                }
            }
            {
                const float* pw = wg + (size_t)(kc + sk) * NO + o0 + se;
                double* dw = &wsh[sk][se];
                #pragma unroll
                for (int e = 0; e < 2; ++e) {
                    float4 f = ((const float4*)pw)[e];
                    d2 lo = {(double)f.x, (double)f.y};
                    d2 hi = {(double)f.z, (double)f.w};
                    *(d2*)(dw + e * 4)     = lo;
                    *(d2*)(dw + e * 4 + 2) = hi;
                }
            }
            __syncthreads();

            #pragma unroll 4
            for (int k = 0; k < KC; ++k) {
                const d2 w2 = *(const d2*)&wsh[k][p2];
                double x8[8];
                #pragma unroll
                for (int e = 0; e < 4; ++e)
                    *(d2*)&x8[e * 2] = *(const d2*)&xs[k][t0 + e * 2];
                #pragma unroll
                for (int j = 0; j < 8; ++j) {
                    a0[j] += x8[j] * w2[0];
                    a1[j] += x8[j] * w2[1];
                }
            }
        }

        __syncthreads();
        #pragma unroll
        for (int j = 0; j < 8; ++j) {
            d2 c = {a0[j], a1[j]};
            *(d2*)&ib[t0 + j][p2] = c;
        }
        __syncthreads();

        if (tid < 64) {
            float* py = yg + ((size_t)(b * NO + o0 + tid)) * NT + tc;
            for (int tb = 0; tb < TT; tb += 16) {
                double iv[16];
                #pragma unroll
                for (int u = 0; u < 16; ++u) iv[u] = ib[tb + u][tid];
                float fv[16];
                #pragma unroll
                for (int u = 0; u < 16; ++u) {
                    v += (iv[u] - v) * alpha;
                    const bool s = (v >= 1.0);
                    fv[u] = s ? 1.0f : 0.0f;
                    if (s) v = 0.0;
                }
                #pragma unroll
                for (int q = 0; q < 4; ++q) {
                    if (tb + q * 4 < tlim)
                        *(float4*)(py + tb + q * 4) =
                            make_float4(fv[q*4], fv[q*4+1], fv[q*4+2], fv[q*4+3]);
                }
            }
        }
    }
}

extern "C" void kernel_launch(void* const* d_in, const int* in_sizes, int n_in,
                              void* d_out, int out_size, void* d_ws, size_t ws_size,
                              hipStream_t stream) {
    const float* x = (const float*)d_in[0];   // [64, 512, 500]
    const float* w = (const float*)d_in[1];   // [512, 512]
    float* y = (float*)d_out;                 // [64, 512, 500]
    (void)in_sizes; (void)n_in; (void)out_size;

    const size_t need = (size_t)NT * BO * sizeof(double);   // 131,072,000 B
    if (ws_size >= need) {
        double* iw = (double*)d_ws;
        snn_gemm<<<2048, 256, 0, stream>>>(x, w, iw);       // 4 blocks/CU
        snn_scan<<<BO / 64, 64, 0, stream>>>(iw, y);        // stream-ordered
    } else {
        snn_v2<<<512, 256, 0, stream>>>(x, w, y);           // proven fallback
    }
}

// Round 6
// 407.962 us; speedup vs baseline: 2.0542x; 1.1767x over previous
//
#include <hip/hip_runtime.h>

// SNN layer on MI355X, two-kernel design.
//   K1 (snn_gemm): i[t, b*512+o] = sum_k x[b,k,t] * w[k,o]  (fp64 -> d_ws)
//   K2 (snn_scan): per-channel sequential LIF over t, spikes fp32 -> d_out
//
// Numerics: spike decision v>=1.0 is razor-thin vs fp32 rounding of i
// (|i|~1.8e5) -> all accumulation + scan in fp64 (rounds 1/4/5 passed,
// absmax 0.0). f64 MFMA faulted twice on gfx950 (and its ceiling == vector
// rate 78.6 TF anyway) -> vector fp64.
//
// Round-5 post-mortem: VALUBusy 48.8% == FMA floor (214us) / 527us; the gap
// was LDS instruction oversubscription (12 scalar b64 reads per 32 FMAs).
// This version: 8t x 8o per thread via contiguous d2 fragments -> 8 b64
// reads per 64 FMAs (256 VALU-cy vs ~50 LDS-cy per wave-k, VALU-bound),
// plus register prefetch of the next K-window to hide HBM under compute.

#define NB 64
#define NI 512
#define NO 512
#define NT 500
#define BO (NB * NO)          // 32768 channels

typedef double d2 __attribute__((ext_vector_type(2)));

// ===================== K1: fp64 GEMM to workspace =====================
#define K1_TT 128             // t-tile
#define K1_OT 128             // o-tile
#define K1_KC 16              // k per LDS window
#define K1_P  130             // padded row (doubles): +2 shifts write banks

__global__ __launch_bounds__(256, 2)
void snn_gemm(const float* __restrict__ xg, const float* __restrict__ wg,
              double* __restrict__ iw) {
    __shared__ double xs[K1_KC][K1_P];    // 16.6 KB
    __shared__ double wsh[K1_KC][K1_P];   // 16.6 KB -> 33.3 KB total

    const int tid = threadIdx.x;
    const int g   = tid & 15;     // o-thread: o-pairs at o0 + 2g + 32q
    const int tt  = tid >> 4;     // t-thread: t-pairs at t0 + 2tt + 32j

    // bijective XCD swizzle (1024 blocks, %8==0): 128 consecutive tiles
    // (= 8 full batches) per XCD -> x[b] and w stay L2-resident.
    const int L    = blockIdx.x;
    const int wgid = (L & 7) * 128 + (L >> 3);
    const int b    = wgid >> 4;               // 16 tiles per batch (4o x 4t)
    const int o0   = ((wgid >> 2) & 3) * K1_OT;
    const int t0   = (wgid & 3) * K1_TT;

    // staging map: row sk (k), 8 consecutive cols at ce
    const int sk = tid >> 4;          // 0..15
    const int ce = (tid & 15) * 8;    // 0..120 (floats/doubles)

    const bool full = (t0 + K1_TT <= NT);   // only t0=384 tile is partial

    float xr[8], wr[8];
    auto load_win = [&](int kc) {
        const float* px = xg + ((size_t)(b * NI + kc + sk)) * NT + t0 + ce;
        if (full) {
            float4 f0 = ((const float4*)px)[0];
            float4 f1 = ((const float4*)px)[1];
            xr[0]=f0.x; xr[1]=f0.y; xr[2]=f0.z; xr[3]=f0.w;
            xr[4]=f1.x; xr[5]=f1.y; xr[6]=f1.z; xr[7]=f1.w;
        } else {
            #pragma unroll
            for (int e = 0; e < 8; ++e)
                xr[e] = (t0 + ce + e < NT) ? px[e] : 0.0f;
        }
        const float* pw = wg + (size_t)(kc + sk) * NO + o0 + ce;
        float4 h0 = ((const float4*)pw)[0];
        float4 h1 = ((const float4*)pw)[1];
        wr[0]=h0.x; wr[1]=h0.y; wr[2]=h0.z; wr[3]=h0.w;
        wr[4]=h1.x; wr[5]=h1.y; wr[6]=h1.z; wr[7]=h1.w;
    };

    double acc[8][8];
    #pragma unroll
    for (int a = 0; a < 8; ++a)
        #pragma unroll
        for (int c = 0; c < 8; ++c) acc[a][c] = 0.0;

    load_win(0);

    for (int kc = 0; kc < NI; kc += K1_KC) {
        __syncthreads();   // previous window's fragment reads complete
        #pragma unroll
        for (int e = 0; e < 8; ++e) {
            xs[sk][ce + e]  = (double)xr[e];
            wsh[sk][ce + e] = (double)wr[e];
        }
        __syncthreads();

        if (kc + K1_KC < NI) load_win(kc + K1_KC);   // hide HBM under compute

        // ---- fp64 inner: 64 FMA per thread per k, 8 b64 reads ----
        // xf: 4 addrs/wave (16-way broadcast). wf: stride 16 B -> 2-way (free).
        #pragma unroll 2
        for (int k = 0; k < K1_KC; ++k) {
            double xf[8], wf[8];
            #pragma unroll
            for (int j = 0; j < 4; ++j)
                *(d2*)&xf[2*j] = *(const d2*)&xs[k][tt*2 + 32*j];
            #pragma unroll
            for (int q = 0; q < 4; ++q)
                *(d2*)&wf[2*q] = *(const d2*)&wsh[k][g*2 + 32*q];
            #pragma unroll
            for (int a = 0; a < 8; ++a)
                #pragma unroll
                for (int c = 0; c < 8; ++c) acc[a][c] += xf[a] * wf[c];
        }
    }

    // ---- store: iw[t][b*NO+o], d2 per (t, o-pair) ----
    double* pb = iw + (size_t)b * NO + o0 + 2 * g;
    #pragma unroll
    for (int a = 0; a < 8; ++a) {
        const int t = t0 + 32 * (a >> 1) + 2 * tt + (a & 1);
        if (t < NT) {
            double* pr = pb + (size_t)t * BO;
            #pragma unroll
            for (int q = 0; q < 4; ++q) {
                d2 c2 = {acc[a][2*q], acc[a][2*q+1]};
                *(d2*)&pr[32 * q] = c2;
            }
        }
    }
}

// ===================== K2: sequential LIF scan =====================
#define SB 20                 // t-batch (500 = 25*20)

__global__ __launch_bounds__(64)
void snn_scan(const double* __restrict__ iw, float* __restrict__ yg) {
    const int ch = blockIdx.x * 64 + threadIdx.x;   // b*512+o
    const double alpha = 0.001 / 50.0;
    double v = 0.0;
    float* py = yg + (size_t)ch * NT;

    for (int tb = 0; tb < NT; tb += SB) {
        double iv[SB];
        #pragma unroll
        for (int u = 0; u < SB; ++u) iv[u] = iw[(size_t)(tb + u) * BO + ch];
        float fv[SB];
        #pragma unroll
        for (int u = 0; u < SB; ++u) {
            v += (iv[u] - v) * alpha;
            const bool s = (v >= 1.0);
            fv[u] = s ? 1.0f : 0.0f;
            if (s) v = 0.0;
        }
        #pragma unroll
        for (int q = 0; q < SB / 4; ++q)
            *(float4*)(py + tb + 4 * q) =
                make_float4(fv[4*q], fv[4*q+1], fv[4*q+2], fv[4*q+3]);
    }
}

// ============ fallback: round-4 fused kernel (proven, ws-free) ============
#define OT 64
#define TT 64
#define KC 32
#define TP (TT + 2)
#define OP (OT + 2)

__global__ __launch_bounds__(256, 2)
void snn_v2(const float* __restrict__ xg, const float* __restrict__ wg,
            float* __restrict__ yg) {
    __shared__ double smem[KC * TP + KC * OP];
    double (*xs)[TP]  = (double(*)[TP])smem;
    double (*wsh)[OP] = (double(*)[OP])(smem + KC * TP);
    double (*ib)[OP]  = (double(*)[OP])smem;

    const int tid = threadIdx.x;
    const int p2  = (tid & 31) * 2;
    const int t0  = (tid >> 5) * 8;

    const int L  = blockIdx.x;
    const int b  = (L & 7) + ((L >> 6) << 3);
    const int o0 = ((L >> 3) & 7) * OT;

    const int sk = tid >> 3;
    const int se = (tid & 7) * 8;

    const double alpha = 0.001 / 50.0;
    double v = 0.0;

    for (int tc = 0; tc < NT; tc += TT) {
        const int tlim = (NT - tc < TT) ? (NT - tc) : TT;

        double a0[8], a1[8];
        #pragma unroll
        for (int j = 0; j < 8; ++j) { a0[j] = 0.0; a1[j] = 0.0; }

        for (int kc = 0; kc < NI; kc += KC) {
            __syncthreads();
            {
                const float* px = xg + ((size_t)(b * NI + kc + sk)) * NT + tc + se;
                double* dx = &xs[sk][se];
                if (tlim == TT) {
                    #pragma unroll
                    for (int e = 0; e < 2; ++e) {
                        float4 f = ((const float4*)px)[e];
                        d2 lo = {(double)f.x, (double)f.y};
                        d2 hi = {(double)f.z, (double)f.w};
                        *(d2*)(dx + e * 4)     = lo;
                        *(d2*)(dx + e * 4 + 2) = hi;
                    }
                } else {
                    #pragma unroll
                    for (int e = 0; e < 8; ++e) {
                        double val = 0.0;
                        if (se + e < tlim) val = (double)px[e];
                        dx[e] = val;
                    }
                }
            }
            {
                const float* pw = wg + (size_t)(kc + sk) * NO + o0 + se;
                double* dw = &wsh[sk][se];
                #pragma unroll
                for (int e = 0; e < 2; ++e) {
                    float4 f = ((const float4*)pw)[e];
                    d2 lo = {(double)f.x, (double)f.y};
                    d2 hi = {(double)f.z, (double)f.w};
                    *(d2*)(dw + e * 4)     = lo;
                    *(d2*)(dw + e * 4 + 2) = hi;
                }
            }
            __syncthreads();

            #pragma unroll 4
            for (int k = 0; k < KC; ++k) {
                const d2 w2 = *(const d2*)&wsh[k][p2];
                double x8[8];
                #pragma unroll
                for (int e = 0; e < 4; ++e)
                    *(d2*)&x8[e * 2] = *(const d2*)&xs[k][t0 + e * 2];
                #pragma unroll
                for (int j = 0; j < 8; ++j) {
                    a0[j] += x8[j] * w2[0];
                    a1[j] += x8[j] * w2[1];
                }
            }
        }

        __syncthreads();
        #pragma unroll
        for (int j = 0; j < 8; ++j) {
            d2 c = {a0[j], a1[j]};
            *(d2*)&ib[t0 + j][p2] = c;
        }
        __syncthreads();

        if (tid < 64) {
            float* py = yg + ((size_t)(b * NO + o0 + tid)) * NT + tc;
            for (int tb = 0; tb < TT; tb += 16) {
                double iv[16];
                #pragma unroll
                for (int u = 0; u < 16; ++u) iv[u] = ib[tb + u][tid];
                float fv[16];
                #pragma unroll
                for (int u = 0; u < 16; ++u) {
                    v += (iv[u] - v) * alpha;
                    const bool s = (v >= 1.0);
                    fv[u] = s ? 1.0f : 0.0f;
                    if (s) v = 0.0;
                }
                #pragma unroll
                for (int q = 0; q < 4; ++q) {
                    if (tb + q * 4 < tlim)
                        *(float4*)(py + tb + q * 4) =
                            make_float4(fv[q*4], fv[q*4+1], fv[q*4+2], fv[q*4+3]);
                }
            }
        }
    }
}

extern "C" void kernel_launch(void* const* d_in, const int* in_sizes, int n_in,
                              void* d_out, int out_size, void* d_ws, size_t ws_size,
                              hipStream_t stream) {
    const float* x = (const float*)d_in[0];   // [64, 512, 500]
    const float* w = (const float*)d_in[1];   // [512, 512]
    float* y = (float*)d_out;                 // [64, 512, 500]
    (void)in_sizes; (void)n_in; (void)out_size;

    const size_t need = (size_t)NT * BO * sizeof(double);   // 131,072,000 B
    if (ws_size >= need) {
        double* iw = (double*)d_ws;
        snn_gemm<<<1024, 256, 0, stream>>>(x, w, iw);
        snn_scan<<<BO / 64, 64, 0, stream>>>(iw, y);        // stream-ordered
    } else {
        snn_v2<<<512, 256, 0, stream>>>(x, w, y);           // proven fallback
    }
}